// Round 2
// baseline (354.849 us; speedup 1.0000x reference)
//
#include <hip/hip_runtime.h>
#include <hip/hip_bf16.h>

// ---------------- GEMM: out[M,256] = A[M,256] @ W[256,256] + bias ----------------
// BM=BN=64, BK=16, 256 threads, 4x4 microtile per thread. All fp32.
__global__ __launch_bounds__(256) void gemm_bias(const float* __restrict__ A,
                                                 const float* __restrict__ W,
                                                 const float* __restrict__ bias,
                                                 float* __restrict__ out, int M) {
    __shared__ __align__(16) float As[16][68];  // As[k][m], pitch 68 (16B-aligned rows)
    __shared__ __align__(16) float Bs[16][68];  // Bs[k][n]

    const int tid = threadIdx.x;
    const int tx = tid & 15;        // n quad
    const int ty = tid >> 4;        // m quad
    const int m0 = blockIdx.y * 64;
    const int n0 = blockIdx.x * 64;
    // A-tile loader: row lam (0..63), k offset lak (0,4,8,12)
    const int lam = tid >> 2;
    const int lak = (tid & 3) * 4;
    // B-tile loader: k row lbk (0..15), n offset lbn
    const int lbk = tid >> 4;
    const int lbn = (tid & 15) * 4;

    float acc[4][4] = {};

    for (int kt = 0; kt < 256; kt += 16) {
        float4 a4 = *(const float4*)&A[(size_t)(m0 + lam) * 256 + kt + lak];
        float4 b4 = *(const float4*)&W[(size_t)(kt + lbk) * 256 + n0 + lbn];
        As[lak + 0][lam] = a4.x;
        As[lak + 1][lam] = a4.y;
        As[lak + 2][lam] = a4.z;
        As[lak + 3][lam] = a4.w;
        *(float4*)&Bs[lbk][lbn] = b4;
        __syncthreads();
#pragma unroll
        for (int kk = 0; kk < 16; ++kk) {
            float4 av = *(const float4*)&As[kk][ty * 4];
            float4 bv = *(const float4*)&Bs[kk][tx * 4];
            acc[0][0] += av.x * bv.x; acc[0][1] += av.x * bv.y; acc[0][2] += av.x * bv.z; acc[0][3] += av.x * bv.w;
            acc[1][0] += av.y * bv.x; acc[1][1] += av.y * bv.y; acc[1][2] += av.y * bv.z; acc[1][3] += av.y * bv.w;
            acc[2][0] += av.z * bv.x; acc[2][1] += av.z * bv.y; acc[2][2] += av.z * bv.z; acc[2][3] += av.z * bv.w;
            acc[3][0] += av.w * bv.x; acc[3][1] += av.w * bv.y; acc[3][2] += av.w * bv.z; acc[3][3] += av.w * bv.w;
        }
        __syncthreads();
    }

#pragma unroll
    for (int i = 0; i < 4; ++i) {
#pragma unroll
        for (int j = 0; j < 4; ++j) {
            out[(size_t)(m0 + ty * 4 + i) * 256 + n0 + tx * 4 + j] =
                acc[i][j] + bias[n0 + tx * 4 + j];
        }
    }
}

// ---------------- attention: one wave per point ----------------
// B=2, N=8192, H=8, HD=32, K=32
#define NPTS 8192

__global__ __launch_bounds__(256) void attn_kernel(
    const float* __restrict__ qf, const float* __restrict__ kf, const float* __restrict__ vf,
    const float* __restrict__ xyz, const int* __restrict__ idx,
    const float* __restrict__ W1, const float* __restrict__ b1,
    const float* __restrict__ W2, const float* __restrict__ b2,
    float* __restrict__ out) {
    __shared__ __align__(16) float q_s[4][256];
    __shared__ float bias_s[4][8 * 33];  // [h][j], pitch 33
    __shared__ float attn_s[4][8 * 33];
    __shared__ int idx_s[4][32];
    __shared__ float W1s[96], b1s[32], W2s[256], b2s[8];

    const int tid = threadIdx.x;
    const int wid = tid >> 6;
    const int lane = tid & 63;
    const int p = blockIdx.x * 4 + wid;  // 0..16383
    const int b = p >> 13;
    const int n = p & 8191;

    // stage tiny MLP weights (block-wide)
    if (tid < 96) W1s[tid] = W1[tid];
    if (tid < 32) b1s[tid] = b1[tid];
    W2s[tid] = W2[tid];
    if (tid < 8) b2s[tid] = b2[tid];

    // stage q (per wave), idx
    ((float4*)q_s[wid])[lane] = ((const float4*)(qf + (size_t)p * 256))[lane];
    if (lane < 32) idx_s[wid][lane] = idx[(size_t)p * 32 + lane];
    __syncthreads();

    // phase 2: bias MLP — lane j < 32 handles neighbor j for all 8 heads
    if (lane < 32) {
        const int j = lane;
        const int nj = idx_s[wid][j];
        const size_t pb = ((size_t)b * NPTS + n) * 3;
        const size_t nb = ((size_t)b * NPTS + nj) * 3;
        const float rx = xyz[pb + 0] - xyz[nb + 0];
        const float ry = xyz[pb + 1] - xyz[nb + 1];
        const float rz = xyz[pb + 2] - xyz[nb + 2];
        float acc[8];
#pragma unroll
        for (int h = 0; h < 8; ++h) acc[h] = b2s[h];
#pragma unroll
        for (int u = 0; u < 32; ++u) {
            float hv = rx * W1s[u] + ry * W1s[32 + u] + rz * W1s[64 + u] + b1s[u];
            hv = fmaxf(hv, 0.f);
#pragma unroll
            for (int h = 0; h < 8; ++h) acc[h] += hv * W2s[u * 8 + h];
        }
#pragma unroll
        for (int h = 0; h < 8; ++h) bias_s[wid][h * 33 + j] = acc[h];
    }
    __syncthreads();

    // phase 3: scores + softmax. lane = (h2, j): j = lane&31, h in {4*h2..4*h2+3}
    {
        const int j = lane & 31;
        const int h2 = lane >> 5;
        const int nj = idx_s[wid][j];
        const float4* kp = (const float4*)(kf + ((size_t)b * NPTS + nj) * 256 + h2 * 128);
        const float4* qp = (const float4*)(q_s[wid] + h2 * 128);
        float sc[4];
#pragma unroll
        for (int c = 0; c < 4; ++c) {
            float d = 0.f;
#pragma unroll
            for (int i = 0; i < 8; ++i) {
                float4 kv = kp[c * 8 + i];
                float4 qv = qp[c * 8 + i];
                d += kv.x * qv.x + kv.y * qv.y + kv.z * qv.z + kv.w * qv.w;
            }
            sc[c] = d * 0.17677669529663687f + bias_s[wid][(h2 * 4 + c) * 33 + j];
        }
#pragma unroll
        for (int c = 0; c < 4; ++c) {
            float m = sc[c];
#pragma unroll
            for (int msk = 16; msk >= 1; msk >>= 1) m = fmaxf(m, __shfl_xor(m, msk, 64));
            float e = __expf(sc[c] - m);
            float s = e;
#pragma unroll
            for (int msk = 16; msk >= 1; msk >>= 1) s += __shfl_xor(s, msk, 64);
            attn_s[wid][(h2 * 4 + c) * 33 + j] = e / s;
        }
    }
    __syncthreads();

    // phase 4: PV. lane = (h, d4): 64 lanes cover the full 256-float row per neighbor
    {
        const int h = lane >> 3;
        const int d4 = (lane & 7) * 4;
        float4 acc = {0.f, 0.f, 0.f, 0.f};
#pragma unroll
        for (int j = 0; j < 32; ++j) {
            const int nj = idx_s[wid][j];
            const float w = attn_s[wid][h * 33 + j];
            float4 v4 = *(const float4*)(vf + ((size_t)b * NPTS + nj) * 256 + h * 32 + d4);
            acc.x += w * v4.x; acc.y += w * v4.y; acc.z += w * v4.z; acc.w += w * v4.w;
        }
        *(float4*)(out + (size_t)p * 256 + h * 32 + d4) = acc;
    }
}

// ---------------- launch ----------------
extern "C" void kernel_launch(void* const* d_in, const int* in_sizes, int n_in,
                              void* d_out, int out_size, void* d_ws, size_t ws_size,
                              hipStream_t stream) {
    const float* x   = (const float*)d_in[0];
    const float* xyz = (const float*)d_in[1];
    const int*   idx = (const int*)d_in[2];
    const float* Wq = (const float*)d_in[3];
    const float* bq = (const float*)d_in[4];
    const float* Wk = (const float*)d_in[5];
    const float* bk = (const float*)d_in[6];
    const float* Wv = (const float*)d_in[7];
    const float* bv = (const float*)d_in[8];
    const float* Wo = (const float*)d_in[9];
    const float* bo = (const float*)d_in[10];
    const float* W1 = (const float*)d_in[11];
    const float* b1 = (const float*)d_in[12];
    const float* W2 = (const float*)d_in[13];
    const float* b2 = (const float*)d_in[14];

    const int M = 16384;  // B*N
    float* qws = (float*)d_ws;           // 16 MB
    float* kws = qws + (size_t)M * 256;  // 16 MB
    float* vws = kws + (size_t)M * 256;  // 16 MB
    float* aout = qws;                   // alias: each wave reads only its own q row
                                         // before writing that same row

    dim3 gg(4, 256), gb(256);
    gemm_bias<<<gg, gb, 0, stream>>>(x, Wq, bq, qws, M);
    gemm_bias<<<gg, gb, 0, stream>>>(x, Wk, bk, kws, M);
    gemm_bias<<<gg, gb, 0, stream>>>(x, Wv, bv, vws, M);

    attn_kernel<<<M / 4, 256, 0, stream>>>(qws, kws, vws, xyz, idx, W1, b1, W2, b2, aout);

    gemm_bias<<<gg, gb, 0, stream>>>(aout, Wo, bo, (float*)d_out, M);
}

// Round 3
// 198.431 us; speedup vs baseline: 1.7883x; 1.7883x over previous
//
#include <hip/hip_runtime.h>
#include <hip/hip_bf16.h>

typedef unsigned int uint32;
typedef unsigned short ushort;
typedef __attribute__((ext_vector_type(4))) float floatx4;
typedef __attribute__((ext_vector_type(8))) __bf16 bf16x8;

#define NPTS 8192

// ---------------- bf16 helpers (RNE) ----------------
__device__ __forceinline__ ushort f2bf(float f) {
    uint32 u = __float_as_uint(f);
    uint32 r = (u + 0x7fffu + ((u >> 16) & 1u)) >> 16;
    return (ushort)r;
}
__device__ __forceinline__ float bf1(ushort u) { return __uint_as_float((uint32)u << 16); }
__device__ __forceinline__ float bflo(uint32 u) { return __uint_as_float(u << 16); }
__device__ __forceinline__ float bfhi(uint32 u) { return __uint_as_float(u & 0xffff0000u); }

// ---------------- cast x -> bf16 ----------------
__global__ __launch_bounds__(256) void cast_x_kernel(const float* __restrict__ x,
                                                     ushort* __restrict__ xb) {
    int i = (blockIdx.x * 256 + threadIdx.x) * 4;
    float4 v = *(const float4*)(x + i);
    ushort4 o;
    o.x = f2bf(v.x); o.y = f2bf(v.y); o.z = f2bf(v.z); o.w = f2bf(v.w);
    *(ushort4*)(xb + i) = o;
}

// ---------------- pack transposed bf16 weights + fused qkv bias ----------------
// Wqkvt[n][k] n in [0,768): seg q/k/v.  Wot[n][k] n in [0,256).
__global__ __launch_bounds__(256) void pack_w_kernel(const float* __restrict__ Wq, const float* __restrict__ Wk,
                                                     const float* __restrict__ Wv, const float* __restrict__ Wo,
                                                     const float* __restrict__ bq, const float* __restrict__ bk,
                                                     const float* __restrict__ bv,
                                                     ushort* __restrict__ Wqkvt, ushort* __restrict__ Wot,
                                                     float* __restrict__ biasqkv) {
    int f = blockIdx.x * 256 + threadIdx.x;  // 0 .. 262143
    if (f < 768 * 256) {
        int n = f >> 8, k = f & 255;
        int seg = n >> 8, nc = n & 255;
        const float* W = (seg == 0) ? Wq : (seg == 1) ? Wk : Wv;
        Wqkvt[f] = f2bf(W[k * 256 + nc]);
    } else {
        int g = f - 768 * 256;
        int n = g >> 8, k = g & 255;
        Wot[g] = f2bf(Wo[k * 256 + n]);
    }
    if (f < 768) biasqkv[f] = (f < 256) ? bq[f] : (f < 512) ? bk[f - 256] : bv[f - 512];
}

// ---------------- MFMA bf16 GEMM: out[M,N] = A[M,256] @ Wt^T + bias ----------------
// A row-major [M][256] bf16; Wt row-major [N][256] bf16 (i.e. W transposed).
// 128x128 tile per block, BK=32, 4 waves in 2x2, each wave 64x64 via 4x4 MFMA 16x16x32.
template <bool OUT_BF16>
__global__ __launch_bounds__(256) void gemm_mfma(const ushort* __restrict__ A,
                                                 const ushort* __restrict__ Wt,
                                                 const float* __restrict__ bias,
                                                 void* __restrict__ outv, int N) {
    __shared__ __align__(16) ushort As[128 * 32];  // [m][k] rows of 64B
    __shared__ __align__(16) ushort Bs[128 * 32];  // [n][k]
    const int tid = threadIdx.x;
    const int w = tid >> 6, lane = tid & 63;
    const int m0 = blockIdx.y * 128, n0 = blockIdx.x * 128;
    const int wm = (w & 1) * 64, wn = (w >> 1) * 64;

    const int lrow = lane >> 2;        // 0..15 row within 16-row chunk
    const int lcol = (lane & 3) * 16;  // byte offset within 64B row

    floatx4 acc[4][4] = {};

    for (int kt = 0; kt < 256; kt += 32) {
        __syncthreads();  // protect LDS from previous iteration's readers
#pragma unroll
        for (int t = 0; t < 2; ++t) {
            const int r = (w * 2 + t) * 16 + lrow;
            const char* ga = (const char*)(A + (size_t)(m0 + r) * 256 + kt) + lcol;
            const char* gb = (const char*)(Wt + (size_t)(n0 + r) * 256 + kt) + lcol;
            __builtin_amdgcn_global_load_lds((const __attribute__((address_space(1))) void*)ga,
                                             (__attribute__((address_space(3))) void*)((char*)As + (w * 2 + t) * 1024),
                                             16, 0, 0);
            __builtin_amdgcn_global_load_lds((const __attribute__((address_space(1))) void*)gb,
                                             (__attribute__((address_space(3))) void*)((char*)Bs + (w * 2 + t) * 1024),
                                             16, 0, 0);
        }
        __syncthreads();  // drains vmcnt (global_load_lds) + makes LDS visible

        bf16x8 af[4], bg[4];
#pragma unroll
        for (int i = 0; i < 4; ++i) {
            af[i] = *(const bf16x8*)&As[(wm + i * 16 + (lane & 15)) * 32 + (lane >> 4) * 8];
            bg[i] = *(const bf16x8*)&Bs[(wn + i * 16 + (lane & 15)) * 32 + (lane >> 4) * 8];
        }
#pragma unroll
        for (int mi = 0; mi < 4; ++mi)
#pragma unroll
            for (int ni = 0; ni < 4; ++ni)
                acc[mi][ni] = __builtin_amdgcn_mfma_f32_16x16x32_bf16(af[mi], bg[ni], acc[mi][ni], 0, 0, 0);
    }

    // epilogue: D[row=(lane>>4)*4+r][col=lane&15] per 16x16 tile
#pragma unroll
    for (int ni = 0; ni < 4; ++ni) {
        const int col = n0 + wn + ni * 16 + (lane & 15);
        const float bv = bias[col];
#pragma unroll
        for (int mi = 0; mi < 4; ++mi) {
            const int row0 = m0 + wm + mi * 16 + (lane >> 4) * 4;
#pragma unroll
            for (int r = 0; r < 4; ++r) {
                const float v = acc[mi][ni][r] + bv;
                if (OUT_BF16)
                    ((ushort*)outv)[(size_t)(row0 + r) * N + col] = f2bf(v);
                else
                    ((float*)outv)[(size_t)(row0 + r) * N + col] = v;
            }
        }
    }
}

// ---------------- attention: one wave per point, bf16 q/k/v ----------------
// qkv row-major [B*N][768]: q at +0, k at +256, v at +512 (bf16)
__global__ __launch_bounds__(256) void attn_kernel(
    const ushort* __restrict__ qkv, const float* __restrict__ xyz, const int* __restrict__ idx,
    const float* __restrict__ W1, const float* __restrict__ b1,
    const float* __restrict__ W2, const float* __restrict__ b2,
    ushort* __restrict__ out) {
    __shared__ __align__(16) float q_s[4][256];
    __shared__ float bias_s[4][8 * 33];
    __shared__ float attn_s[4][8 * 33];
    __shared__ int idx_s[4][32];
    __shared__ float W1s[96], b1s[32], W2s[256], b2s[8];

    const int tid = threadIdx.x;
    const int wid = tid >> 6;
    const int lane = tid & 63;
    const int p = blockIdx.x * 4 + wid;
    const int b = p >> 13;
    const int n = p & 8191;

    if (tid < 96) W1s[tid] = W1[tid];
    if (tid < 32) b1s[tid] = b1[tid];
    W2s[tid] = W2[tid];
    if (tid < 8) b2s[tid] = b2[tid];

    // stage q (bf16 -> fp32 LDS)
    {
        ushort4 qa = ((const ushort4*)(qkv + (size_t)p * 768))[lane];
        float4 q4;
        q4.x = bf1(qa.x); q4.y = bf1(qa.y); q4.z = bf1(qa.z); q4.w = bf1(qa.w);
        *(float4*)&q_s[wid][lane * 4] = q4;
    }
    if (lane < 32) idx_s[wid][lane] = idx[(size_t)p * 32 + lane];
    __syncthreads();

    // bias MLP: lane j < 32 handles neighbor j for all 8 heads
    if (lane < 32) {
        const int j = lane;
        const int nj = idx_s[wid][j];
        const size_t pb = ((size_t)b * NPTS + n) * 3;
        const size_t nb = ((size_t)b * NPTS + nj) * 3;
        const float rx = xyz[pb + 0] - xyz[nb + 0];
        const float ry = xyz[pb + 1] - xyz[nb + 1];
        const float rz = xyz[pb + 2] - xyz[nb + 2];
        float acc[8];
#pragma unroll
        for (int h = 0; h < 8; ++h) acc[h] = b2s[h];
#pragma unroll
        for (int u = 0; u < 32; ++u) {
            float hv = rx * W1s[u] + ry * W1s[32 + u] + rz * W1s[64 + u] + b1s[u];
            hv = fmaxf(hv, 0.f);
#pragma unroll
            for (int h = 0; h < 8; ++h) acc[h] += hv * W2s[u * 8 + h];
        }
#pragma unroll
        for (int h = 0; h < 8; ++h) bias_s[wid][h * 33 + j] = acc[h];
    }
    __syncthreads();

    // scores + softmax: j = lane&31 (neighbor), h2 = lane>>5 (head-half)
    {
        const int j = lane & 31;
        const int h2 = lane >> 5;
        const int nj = idx_s[wid][j];
        const size_t pn = (size_t)b * NPTS + nj;
        const uint32* kp = (const uint32*)(qkv + pn * 768 + 256) + h2 * 64;  // 128 bf16 = 64 uints
        float sc[4];
#pragma unroll
        for (int c = 0; c < 4; ++c) {
            const float* qc = &q_s[wid][h2 * 128 + c * 32];
            float d = 0.f;
#pragma unroll
            for (int i = 0; i < 4; ++i) {
                uint4 kv = ((const uint4*)(kp + c * 16))[i];  // 8 bf16
                const float* q8 = qc + i * 8;
                d += bflo(kv.x) * q8[0] + bfhi(kv.x) * q8[1]
                   + bflo(kv.y) * q8[2] + bfhi(kv.y) * q8[3]
                   + bflo(kv.z) * q8[4] + bfhi(kv.z) * q8[5]
                   + bflo(kv.w) * q8[6] + bfhi(kv.w) * q8[7];
            }
            sc[c] = d * 0.17677669529663687f + bias_s[wid][(h2 * 4 + c) * 33 + j];
        }
#pragma unroll
        for (int c = 0; c < 4; ++c) {
            float m = sc[c];
#pragma unroll
            for (int msk = 16; msk >= 1; msk >>= 1) m = fmaxf(m, __shfl_xor(m, msk, 64));
            float e = __expf(sc[c] - m);
            float s = e;
#pragma unroll
            for (int msk = 16; msk >= 1; msk >>= 1) s += __shfl_xor(s, msk, 64);
            attn_s[wid][(h2 * 4 + c) * 33 + j] = e / s;
        }
    }
    __syncthreads();

    // PV: h = lane>>3, d4 = (lane&7)*4; 64 lanes cover the 256-elem row per neighbor
    {
        const int h = lane >> 3;
        const int d4 = (lane & 7) * 4;
        float4 acc = {0.f, 0.f, 0.f, 0.f};
#pragma unroll
        for (int j = 0; j < 32; ++j) {
            const int nj = idx_s[wid][j];
            const float wgt = attn_s[wid][h * 33 + j];
            ushort4 v4 = *(const ushort4*)(qkv + ((size_t)b * NPTS + nj) * 768 + 512 + h * 32 + d4);
            acc.x += wgt * bf1(v4.x);
            acc.y += wgt * bf1(v4.y);
            acc.z += wgt * bf1(v4.z);
            acc.w += wgt * bf1(v4.w);
        }
        ushort4 o;
        o.x = f2bf(acc.x); o.y = f2bf(acc.y); o.z = f2bf(acc.z); o.w = f2bf(acc.w);
        *(ushort4*)(out + (size_t)p * 256 + h * 32 + d4) = o;
    }
}

// ---------------- launch ----------------
extern "C" void kernel_launch(void* const* d_in, const int* in_sizes, int n_in,
                              void* d_out, int out_size, void* d_ws, size_t ws_size,
                              hipStream_t stream) {
    const float* x   = (const float*)d_in[0];
    const float* xyz = (const float*)d_in[1];
    const int*   idx = (const int*)d_in[2];
    const float* Wq = (const float*)d_in[3];
    const float* bq = (const float*)d_in[4];
    const float* Wk = (const float*)d_in[5];
    const float* bk = (const float*)d_in[6];
    const float* Wv = (const float*)d_in[7];
    const float* bv = (const float*)d_in[8];
    const float* Wo = (const float*)d_in[9];
    const float* bo = (const float*)d_in[10];
    const float* W1 = (const float*)d_in[11];
    const float* b1 = (const float*)d_in[12];
    const float* W2 = (const float*)d_in[13];
    const float* b2 = (const float*)d_in[14];

    const int M = 16384;  // B*N
    char* wsb = (char*)d_ws;
    ushort* x_bf    = (ushort*)wsb;                            // 8 MB
    ushort* qkv_bf  = (ushort*)(wsb + 8388608);                // 25.17 MB
    ushort* aout_bf = (ushort*)(wsb + 8388608 + 25165824);     // 8 MB
    ushort* Wqkvt   = (ushort*)(wsb + 41943040);               // 384 KB
    ushort* Wot     = (ushort*)(wsb + 42336256);               // 128 KB
    float*  biasqkv = (float*)(wsb + 42467328);                // 3 KB

    cast_x_kernel<<<(M * 256 / 4) / 256, 256, 0, stream>>>(x, x_bf);
    pack_w_kernel<<<(768 * 256 + 256 * 256) / 256, 256, 0, stream>>>(
        Wq, Wk, Wv, Wo, bq, bk, bv, Wqkvt, Wot, biasqkv);

    gemm_mfma<true><<<dim3(6, 128), 256, 0, stream>>>(x_bf, Wqkvt, biasqkv, qkv_bf, 768);

    attn_kernel<<<M / 4, 256, 0, stream>>>(qkv_bf, xyz, idx, W1, b1, W2, b2, aout_bf);

    gemm_mfma<false><<<dim3(2, 128), 256, 0, stream>>>(aout_bf, Wot, bo, d_out, 256);
}